// Round 1
// baseline (70.637 us; speedup 1.0000x reference)
//
#include <hip/hip_runtime.h>

// Closed-form quanv: the 4-qubit circuit + Z-measurement collapses algebraically.
//
// Derivation (verified via Heisenberg back-propagation AND product-state
// factorization; q=0 limit checks out):
//   - RY(q1,w1) commutes past RX(q0,w0) and merges into data RY: a1' = a1+q1.
//   - RX(q3,w3) commutes past CNOT(0,1), RZ(q2,w2), RX(q0,w0).
//   - State stays (w0,w1)-block (x) (w2,w3)-block product through CNOT(0,1),
//     CNOT(2,3), RY(q4,w2); final CNOT(1,2) only permutes B-indices per i1,
//     so measurement probabilities factorize: p[i] = PA[i0,i1]*PB[i2^i1,i3].
//   Resulting Z-expectations:
//     f0 = cos(q0)*cos(a0)
//     f1 = f0*cos(a1+q1)
//     f2 = f1*(cos(q4)*cos(a2) - sin(q4)*cos(q2)*sin(a2)*sin(a3))
//     f3 = cos(q3)*cos(a2)*cos(a3)
//
// Phase 2/3 (linear layer + log_softmax) unchanged from the verified kernel.
__global__ __launch_bounds__(256) void quanv_fused(
    const float* __restrict__ x,      // (B, 784)
    const float* __restrict__ embW,   // (4, 4) row-major
    const float* __restrict__ embB,   // (4,)
    const float* __restrict__ qp,     // (5,)
    const float* __restrict__ linW,   // (10, 784) row-major
    const float* __restrict__ linB,   // (10,)
    float* __restrict__ out)          // (B, 10)
{
    const int b   = blockIdx.x;
    const int tid = threadIdx.x;

    __shared__ float4 sfeats[196];   // feats per patch
    __shared__ float  slog[10];

    if (tid < 196) {
        const unsigned pi = (unsigned)tid / 14u, pj = (unsigned)tid % 14u;
        const float* img = x + (size_t)b * 784;
        // 2x2 patch as two aligned float2 loads (byte offset is 8-aligned: even*4).
        const float2 r0 = *reinterpret_cast<const float2*>(img + (2 * pi) * 28 + 2 * pj);
        const float2 r1 = *reinterpret_cast<const float2*>(img + (2 * pi + 1) * 28 + 2 * pj);
        const float p0 = r0.x, p1 = r0.y, p2 = r1.x, p3 = r1.y;

        // Angles: ang[w] = patch . embW[w,:] + embB[w]  (full angles, not halves)
        float a0 = embB[0] + embW[0] * p0 + embW[1] * p1 + embW[2]  * p2 + embW[3]  * p3;
        float a1 = embB[1] + embW[4] * p0 + embW[5] * p1 + embW[6]  * p2 + embW[7]  * p3;
        float a2 = embB[2] + embW[8] * p0 + embW[9] * p1 + embW[10] * p2 + embW[11] * p3;
        float a3 = embB[3] + embW[12] * p0 + embW[13] * p1 + embW[14] * p2 + embW[15] * p3;

        // Uniform circuit constants (scalarized by the compiler: literal indices,
        // lane-uniform). Full angles of q_params.
        const float Q0 = __cosf(qp[0]);
        float s4, c4;
        __sincosf(qp[4], &s4, &c4);
        const float S4C2 = s4 * __cosf(qp[2]);
        const float Q3 = __cosf(qp[3]);

        const float c0 = __cosf(a0);
        const float c1 = __cosf(a1 + qp[1]);
        float s2, c2; __sincosf(a2, &s2, &c2);
        float s3, c3; __sincosf(a3, &s3, &c3);

        const float f0 = Q0 * c0;
        const float f1 = f0 * c1;
        const float f2 = f1 * (c4 * c2 - S4C2 * s2 * s3);
        const float f3 = Q3 * c2 * c3;

        sfeats[tid] = make_float4(f0, f1, f2, f3);
    }
    __syncthreads();

    // Channel-split dot + reduce: thread (c, j) handles channel c, patches j::16.
    if (tid < 160) {
        const int c = tid >> 4;
        const int j = tid & 15;
        float acc = 0.0f;
        for (int p = j; p < 196; p += 16) {
            const float4 f  = sfeats[p];
            const float4 wv = *reinterpret_cast<const float4*>(linW + c * 784 + p * 4);
            acc += f.x * wv.x + f.y * wv.y + f.z * wv.z + f.w * wv.w;
        }
        // 16-lane group reduce (groups are 16-aligned; xor stays in-group).
        acc += __shfl_xor(acc, 8);
        acc += __shfl_xor(acc, 4);
        acc += __shfl_xor(acc, 2);
        acc += __shfl_xor(acc, 1);
        if (j == 0) slog[c] = acc;
    }
    __syncthreads();

    // log_softmax across 10 classes, parallel over the first 16 lanes.
    if (tid < 16) {
        const float logit = (tid < 10) ? (slog[tid] + linB[tid]) : -1e30f;
        float m = logit;
        m = fmaxf(m, __shfl_xor(m, 1, 16));
        m = fmaxf(m, __shfl_xor(m, 2, 16));
        m = fmaxf(m, __shfl_xor(m, 4, 16));
        m = fmaxf(m, __shfl_xor(m, 8, 16));
        float e = (tid < 10) ? expf(logit - m) : 0.0f;
        e += __shfl_xor(e, 1, 16);
        e += __shfl_xor(e, 2, 16);
        e += __shfl_xor(e, 4, 16);
        e += __shfl_xor(e, 8, 16);
        const float lse = m + logf(e);
        if (tid < 10) out[(size_t)b * 10 + tid] = logit - lse;
    }
}

extern "C" void kernel_launch(void* const* d_in, const int* in_sizes, int n_in,
                              void* d_out, int out_size, void* d_ws, size_t ws_size,
                              hipStream_t stream) {
    const float* x    = (const float*)d_in[0];
    const float* embW = (const float*)d_in[1];
    const float* embB = (const float*)d_in[2];
    const float* qp   = (const float*)d_in[3];
    const float* linW = (const float*)d_in[4];
    const float* linB = (const float*)d_in[5];
    float* out = (float*)d_out;

    const int B = in_sizes[0] / 784;
    quanv_fused<<<B, 256, 0, stream>>>(x, embW, embB, qp, linW, linB, out);
}